// Round 1
// baseline (807.348 us; speedup 1.0000x reference)
//
#include <hip/hip_runtime.h>

// BERT self-attention fused forward, MI355X (gfx950)
// B=4, S=2048, E=768, H=12, D=64
// Stage 1: convert hidden + weights to bf16
// Stage 2: QKV GEMM (bf16 MFMA 16x16x32), bias + 1/sqrt(D) fused; Q,K in [B,H,S,D], V transposed [B,H,D,S]
// Stage 3: flash attention, 64-row Q tiles, 64-key tiles, online softmax, masks in fp32

typedef __bf16 bf16x8 __attribute__((ext_vector_type(8)));
typedef float f32x4 __attribute__((ext_vector_type(4)));

#define MFMA16(a, b, c) __builtin_amdgcn_mfma_f32_16x16x32_bf16((a), (b), (c), 0, 0, 0)

__device__ __forceinline__ unsigned short f32_to_bf16(float f) {
    unsigned int u = __builtin_bit_cast(unsigned int, f);
    u += 0x7FFFu + ((u >> 16) & 1u);   // round-to-nearest-even
    return (unsigned short)(u >> 16);
}

__global__ __launch_bounds__(256) void cvt_f32_bf16(const float* __restrict__ src,
                                                    unsigned short* __restrict__ dst, int n4) {
    int i = blockIdx.x * 256 + threadIdx.x;
    if (i < n4) {
        const float4 v = reinterpret_cast<const float4*>(src)[i];
        ushort4 o;
        o.x = f32_to_bf16(v.x);
        o.y = f32_to_bf16(v.y);
        o.z = f32_to_bf16(v.z);
        o.w = f32_to_bf16(v.w);
        reinterpret_cast<ushort4*>(dst)[i] = o;
    }
}

// QKV GEMM: out[m][n] = sum_k X[m][k] * W[n][k] + bias[n]
// M = 8192 (B*S), N = 2304 (3*E), K = 768.
// Block 256 thr = 4 waves; block tile 64(M) x 64(N); wave tile 16(M) x 64(N).
// A-frag: lane l elem j = X[m0 + (l&15)][k + 8*(l>>4) + j]
// B-frag: lane l elem j = W[n0 + (l&15)][k + 8*(l>>4) + j]   (B[k][n] = W[n][k])
// D: row = (l>>4)*4 + i, col = l&15
__global__ __launch_bounds__(256) void qkv_gemm(const unsigned short* __restrict__ Xb,
                                                const unsigned short* __restrict__ Wb,
                                                const float* __restrict__ bq,
                                                const float* __restrict__ bk,
                                                const float* __restrict__ bv,
                                                unsigned short* __restrict__ Qb,
                                                unsigned short* __restrict__ Kb,
                                                unsigned short* __restrict__ Vt) {
    const int K = 768;
    const int lane = threadIdx.x & 63;
    const int w    = threadIdx.x >> 6;
    const int col  = lane & 15;
    const int g    = lane >> 4;

    const int m0 = blockIdx.y * 64 + w * 16;
    const int n0 = blockIdx.x * 64;

    const unsigned short* arow = Xb + (size_t)(m0 + col) * K + 8 * g;

    f32x4 acc[4] = {};
    for (int k = 0; k < K; k += 32) {
        bf16x8 a = *reinterpret_cast<const bf16x8*>(arow + k);
#pragma unroll
        for (int s = 0; s < 4; ++s) {
            bf16x8 b = *reinterpret_cast<const bf16x8*>(Wb + (size_t)(n0 + s * 16 + col) * K + k + 8 * g);
            acc[s] = MFMA16(a, b, acc[s]);
        }
    }

    const int which = n0 / 768;  // 0=Q,1=K,2=V (uniform per block; 768 % 64 == 0)
    const float* bias = (which == 0) ? bq : (which == 1) ? bk : bv;
    const float scale = (which == 0) ? 0.125f : 1.0f;  // 1/sqrt(64) folded into Q

#pragma unroll
    for (int s = 0; s < 4; ++s) {
        const int n = n0 + s * 16 + col;
        const int e = n - which * 768;
        const int h = e >> 6;
        const int d = e & 63;
        const float bb = bias[e];
#pragma unroll
        for (int i = 0; i < 4; ++i) {
            const int m    = m0 + 4 * g + i;
            const int bsel = m >> 11;
            const int srow = m & 2047;
            const int bh   = bsel * 12 + h;
            const float v  = (acc[s][i] + bb) * scale;
            if (which == 0) {
                Qb[((size_t)bh * 2048 + srow) * 64 + d] = f32_to_bf16(v);
            } else if (which == 1) {
                Kb[((size_t)bh * 2048 + srow) * 64 + d] = f32_to_bf16(v);
            } else {
                // V stored transposed: Vt[bh][d][s] so PV B-frags are contiguous
                Vt[((size_t)bh * 64 + d) * 2048 + srow] = f32_to_bf16(v);
            }
        }
    }
}

// Flash attention: grid (S/64, B*H); block 256 = 4 waves; wave owns 16 q rows.
__global__ __launch_bounds__(256) void attn_kernel(const unsigned short* __restrict__ Qb,
                                                   const unsigned short* __restrict__ Kb,
                                                   const unsigned short* __restrict__ Vt,
                                                   const float* __restrict__ amask,
                                                   const float* __restrict__ dmask,
                                                   float* __restrict__ out) {
    const int S = 2048, D = 64, H = 12;
    const int lane = threadIdx.x & 63;
    const int w    = threadIdx.x >> 6;
    const int col  = lane & 15;
    const int g    = lane >> 4;

    const int bh = blockIdx.y;        // 0..47
    const int b  = bh / H;
    const int h  = bh % H;
    const int q0 = blockIdx.x * 64 + w * 16;   // this wave's first q row

    // Q fragments (Q pre-scaled by 1/sqrt(D))
    const unsigned short* Qp = Qb + ((size_t)bh * S + q0 + col) * D + 8 * g;
    const bf16x8 aq0 = *reinterpret_cast<const bf16x8*>(Qp);
    const bf16x8 aq1 = *reinterpret_cast<const bf16x8*>(Qp + 32);

    f32x4 octx[4] = {};
    float m_run[4], l_run[4];
#pragma unroll
    for (int i = 0; i < 4; ++i) { m_run[i] = -1e30f; l_run[i] = 0.0f; }

    __shared__ unsigned short Plds[4][16][72];   // per-wave P tile (16 q x 64 keys), +8 pad

    const float* am    = amask + (size_t)b * S;
    const float* dmrow = dmask + (size_t)b * S * S;

    for (int kv = 0; kv < S; kv += 64) {
        // ---- QK^T: 16 q x 64 keys ----
        f32x4 sc[4] = {};
#pragma unroll
        for (int s = 0; s < 4; ++s) {
            const unsigned short* Kp = Kb + ((size_t)bh * S + kv + s * 16 + col) * D + 8 * g;
            bf16x8 b0 = *reinterpret_cast<const bf16x8*>(Kp);
            bf16x8 b1 = *reinterpret_cast<const bf16x8*>(Kp + 32);
            sc[s] = MFMA16(aq0, b0, sc[s]);
            sc[s] = MFMA16(aq1, b1, sc[s]);
        }
        // ---- masks (fp32 exact) ----
#pragma unroll
        for (int s = 0; s < 4; ++s) {
            const float a = am[kv + s * 16 + col];
#pragma unroll
            for (int i = 0; i < 4; ++i) {
                const int q = q0 + 4 * g + i;
                sc[s][i] += a + dmrow[(size_t)q * S + kv + s * 16 + col];
            }
        }
        // ---- online softmax: row max over 64 keys ----
        float tm[4], mn[4], sf[4];
#pragma unroll
        for (int i = 0; i < 4; ++i)
            tm[i] = fmaxf(fmaxf(sc[0][i], sc[1][i]), fmaxf(sc[2][i], sc[3][i]));
#pragma unroll
        for (int off = 1; off <= 8; off <<= 1) {
#pragma unroll
            for (int i = 0; i < 4; ++i) tm[i] = fmaxf(tm[i], __shfl_xor(tm[i], off));
        }
#pragma unroll
        for (int i = 0; i < 4; ++i) {
            mn[i] = fmaxf(m_run[i], tm[i]);
            sf[i] = __expf(m_run[i] - mn[i]);   // 0 on first iter (exp(-inf))
            m_run[i] = mn[i];
        }
        // ---- P = exp(s - m), row sums ----
        float rs[4] = {0.f, 0.f, 0.f, 0.f};
#pragma unroll
        for (int s = 0; s < 4; ++s)
#pragma unroll
            for (int i = 0; i < 4; ++i) {
                const float p = __expf(sc[s][i] - mn[i]);
                sc[s][i] = p;
                rs[i] += p;
            }
#pragma unroll
        for (int off = 1; off <= 8; off <<= 1) {
#pragma unroll
            for (int i = 0; i < 4; ++i) rs[i] += __shfl_xor(rs[i], off);
        }
#pragma unroll
        for (int i = 0; i < 4; ++i) l_run[i] = l_run[i] * sf[i] + rs[i];
        // rescale running context
#pragma unroll
        for (int ds_ = 0; ds_ < 4; ++ds_)
#pragma unroll
            for (int i = 0; i < 4; ++i) octx[ds_][i] *= sf[i];

        // ---- P (C-layout) -> LDS -> A-layout for PV ----
        __syncthreads();
#pragma unroll
        for (int s = 0; s < 4; ++s)
#pragma unroll
            for (int i = 0; i < 4; ++i)
                Plds[w][4 * g + i][s * 16 + col] = f32_to_bf16(sc[s][i]);
        __syncthreads();

        // ---- PV: ctx[16 q][64 d] += P[16 q][64 k] * V[64 k][64 d] ----
#pragma unroll
        for (int t = 0; t < 2; ++t) {
            bf16x8 ap = *reinterpret_cast<const bf16x8*>(&Plds[w][col][t * 32 + 8 * g]);
#pragma unroll
            for (int ds_ = 0; ds_ < 4; ++ds_) {
                // B[k=key][n=d] = V[key][d] = Vt[d][key] -> contiguous 16B load
                bf16x8 bv = *reinterpret_cast<const bf16x8*>(
                    Vt + ((size_t)bh * 64 + ds_ * 16 + col) * 2048 + kv + t * 32 + 8 * g);
                octx[ds_] = MFMA16(ap, bv, octx[ds_]);
            }
        }
    }

    // ---- epilogue: out[b][q][h*64 + d] = ctx / l ----
#pragma unroll
    for (int ds_ = 0; ds_ < 4; ++ds_) {
#pragma unroll
        for (int i = 0; i < 4; ++i) {
            const int q = q0 + 4 * g + i;
            out[((size_t)b * S + q) * 768 + h * 64 + ds_ * 16 + col] = octx[ds_][i] / l_run[i];
        }
    }
}

extern "C" void kernel_launch(void* const* d_in, const int* in_sizes, int n_in,
                              void* d_out, int out_size, void* d_ws, size_t ws_size,
                              hipStream_t stream) {
    const float* hidden = (const float*)d_in[0];
    const float* amask  = (const float*)d_in[1];
    const float* dmask  = (const float*)d_in[2];
    const float* Wq     = (const float*)d_in[3];
    const float* bq     = (const float*)d_in[4];
    const float* Wk     = (const float*)d_in[5];
    const float* bk     = (const float*)d_in[6];
    const float* Wv     = (const float*)d_in[7];
    const float* bv     = (const float*)d_in[8];
    float* out = (float*)d_out;

    // workspace layout (bf16 elements)
    unsigned short* Xb = (unsigned short*)d_ws;      // 8192*768      = 6291456
    unsigned short* Wb = Xb + 6291456;               // 2304*768      = 1769472
    unsigned short* Qb = Wb + 1769472;               // 48*2048*64    = 6291456
    unsigned short* Kb = Qb + 6291456;
    unsigned short* Vt = Kb + 6291456;               // transposed [bh][d][s]

    // stage 1: fp32 -> bf16
    cvt_f32_bf16<<<6291456 / 4 / 256, 256, 0, stream>>>(hidden, Xb, 6291456 / 4);
    cvt_f32_bf16<<<576, 256, 0, stream>>>(Wq, Wb,           147456);
    cvt_f32_bf16<<<576, 256, 0, stream>>>(Wk, Wb + 589824,  147456);
    cvt_f32_bf16<<<576, 256, 0, stream>>>(Wv, Wb + 1179648, 147456);

    // stage 2: QKV projection (M=8192, N=2304)
    qkv_gemm<<<dim3(36, 128), 256, 0, stream>>>(Xb, Wb, bq, bk, bv, Qb, Kb, Vt);

    // stage 3: attention
    attn_kernel<<<dim3(32, 48), 256, 0, stream>>>(Qb, Kb, Vt, amask, dmask, out);
}

// Round 3
// 645.556 us; speedup vs baseline: 1.2506x; 1.2506x over previous
//
#include <hip/hip_runtime.h>

// BERT self-attention fused forward, MI355X (gfx950)
// B=4, S=2048, E=768, H=12, D=64
// Round 2 (resubmit after infra timeout):
//  - qkv_gemm: m97-style 128x128 LDS-staged tile (global_load_lds w=16), BK=32
//  - attn: fully swapped MFMAs (q = lane col throughout), coalesced float4 dmask
//    with 2-deep prefetch, amask in LDS, no per-tile barriers, exact defer-rescale,
//    XCD-bijective block swizzle.

typedef __bf16 bf16x8 __attribute__((ext_vector_type(8)));
typedef float f32x4 __attribute__((ext_vector_type(4)));

#define MFMA16(a, b, c) __builtin_amdgcn_mfma_f32_16x16x32_bf16((a), (b), (c), 0, 0, 0)

__device__ __forceinline__ unsigned short f32_to_bf16(float f) {
    unsigned int u = __builtin_bit_cast(unsigned int, f);
    u += 0x7FFFu + ((u >> 16) & 1u);   // round-to-nearest-even
    return (unsigned short)(u >> 16);
}

__device__ __forceinline__ void gload_lds16(const void* g, void* l) {
    __builtin_amdgcn_global_load_lds(
        (const __attribute__((address_space(1))) void*)g,
        (__attribute__((address_space(3))) void*)l, 16, 0, 0);
}

__global__ __launch_bounds__(256) void cvt_f32_bf16(const float* __restrict__ src,
                                                    unsigned short* __restrict__ dst, int n4) {
    int i = blockIdx.x * 256 + threadIdx.x;
    if (i < n4) {
        const float4 v = reinterpret_cast<const float4*>(src)[i];
        ushort4 o;
        o.x = f32_to_bf16(v.x);
        o.y = f32_to_bf16(v.y);
        o.z = f32_to_bf16(v.z);
        o.w = f32_to_bf16(v.w);
        reinterpret_cast<ushort4*>(dst)[i] = o;
    }
}

// all three weight matrices in one launch; i indexes float4 units
__global__ __launch_bounds__(256) void cvt_weights(const float* __restrict__ Wq,
                                                   const float* __restrict__ Wk,
                                                   const float* __restrict__ Wv,
                                                   unsigned short* __restrict__ Wb) {
    int i = blockIdx.x * 256 + threadIdx.x;   // 0 .. 3*147456-1
    const float* src;
    int local = i;
    if (i < 147456) {
        src = Wq;
    } else if (i < 294912) {
        src = Wk; local = i - 147456;
    } else {
        src = Wv; local = i - 294912;
    }
    const float4 v = reinterpret_cast<const float4*>(src)[local];
    ushort4 o;
    o.x = f32_to_bf16(v.x);
    o.y = f32_to_bf16(v.y);
    o.z = f32_to_bf16(v.z);
    o.w = f32_to_bf16(v.w);
    reinterpret_cast<ushort4*>(Wb)[i] = o;
}

// QKV GEMM, m97 structure: out[m][n] = sum_k X[m][k]*W[n][k] + bias[n]
// M=8192, N=2304, K=768. Block 256 thr (4 waves 2x2), tile 128x128, BK=32.
__global__ __launch_bounds__(256) void qkv_gemm(const unsigned short* __restrict__ Xb,
                                                const unsigned short* __restrict__ Wb,
                                                const float* __restrict__ bq,
                                                const float* __restrict__ bk,
                                                const float* __restrict__ bv,
                                                unsigned short* __restrict__ Qb,
                                                unsigned short* __restrict__ Kb,
                                                unsigned short* __restrict__ Vt) {
    const int K = 768;
    __shared__ __align__(16) unsigned short Abuf[128 * 32];
    __shared__ __align__(16) unsigned short Bbuf[128 * 32];

    const int lane = threadIdx.x & 63;
    const int w    = threadIdx.x >> 6;
    const int col  = lane & 15;
    const int g    = lane >> 4;
    const int m0 = blockIdx.y * 128;
    const int n0 = blockIdx.x * 128;
    const int wm = w >> 1, wn = w & 1;

    // staging: wave w covers rows [w*16, w*16+16) (call 0) and +64 (call 1);
    // lane t: row += t/4, col = (t%4)*8 bf16. LDS dest = base + lane*16 (linear).
    const int srow = w * 16 + (lane >> 2);
    const int scol = (lane & 3) * 8;
    const unsigned short* gA0 = Xb + (size_t)(m0 + srow) * K + scol;
    const unsigned short* gA1 = gA0 + (size_t)64 * K;
    const unsigned short* gB0 = Wb + (size_t)(n0 + srow) * K + scol;
    const unsigned short* gB1 = gB0 + (size_t)64 * K;
    char* lA0 = (char*)Abuf + w * 1024;
    char* lA1 = (char*)Abuf + 4096 + w * 1024;
    char* lB0 = (char*)Bbuf + w * 1024;
    char* lB1 = (char*)Bbuf + 4096 + w * 1024;

    f32x4 acc[4][4] = {};
    for (int k0 = 0; k0 < K; k0 += 32) {
        __syncthreads();
        gload_lds16(gA0 + k0, lA0);
        gload_lds16(gA1 + k0, lA1);
        gload_lds16(gB0 + k0, lB0);
        gload_lds16(gB1 + k0, lB1);
        __syncthreads();
        bf16x8 a[4], bfr[4];
#pragma unroll
        for (int t = 0; t < 4; ++t) {
            a[t]   = *reinterpret_cast<const bf16x8*>(Abuf + (wm * 64 + t * 16 + col) * 32 + 8 * g);
            bfr[t] = *reinterpret_cast<const bf16x8*>(Bbuf + (wn * 64 + t * 16 + col) * 32 + 8 * g);
        }
#pragma unroll
        for (int mi = 0; mi < 4; ++mi)
#pragma unroll
            for (int ni = 0; ni < 4; ++ni)
                acc[mi][ni] = MFMA16(a[mi], bfr[ni], acc[mi][ni]);
    }

    const int which = n0 / 768;  // 0=Q,1=K,2=V (uniform: 768 % 128 == 0)
    const float* bias = (which == 0) ? bq : (which == 1) ? bk : bv;
    const float scale = (which == 0) ? 0.125f : 1.0f;  // fold 1/sqrt(64) into Q

#pragma unroll
    for (int ni = 0; ni < 4; ++ni) {
        const int n = n0 + wn * 64 + ni * 16 + col;
        const int e = n - which * 768;
        const int h = e >> 6;
        const int d = e & 63;
        const float bb = bias[e];
#pragma unroll
        for (int mi = 0; mi < 4; ++mi)
#pragma unroll
            for (int i = 0; i < 4; ++i) {
                const int m   = m0 + wm * 64 + mi * 16 + 4 * g + i;
                const int bh  = (m >> 11) * 12 + h;
                const int srw = m & 2047;
                const float v = (acc[mi][ni][i] + bb) * scale;
                const unsigned short bfv = f32_to_bf16(v);
                if (which == 0)      Qb[((size_t)bh * 2048 + srw) * 64 + d] = bfv;
                else if (which == 1) Kb[((size_t)bh * 2048 + srw) * 64 + d] = bfv;
                else                 Vt[((size_t)bh * 64 + d) * 2048 + srw] = bfv;  // V transposed
            }
    }
}

// Flash attention, fully swapped layout (q = lane col everywhere).
// 1-D grid 1536 (XCD-swizzled -> bh, qtile); 4 waves; wave owns 16 q rows.
__global__ __launch_bounds__(256) void attn_kernel(const unsigned short* __restrict__ Qb,
                                                   const unsigned short* __restrict__ Kb,
                                                   const unsigned short* __restrict__ Vt,
                                                   const float* __restrict__ amask,
                                                   const float* __restrict__ dmask,
                                                   float* __restrict__ out) {
    const int S = 2048, H = 12;
    const int lane = threadIdx.x & 63;
    const int w    = threadIdx.x >> 6;
    const int col  = lane & 15;
    const int g    = lane >> 4;

    // bijective XCD swizzle: 1536 blocks, 192 consecutive logicals per XCD
    const int phys    = blockIdx.x;
    const int logical = (phys & 7) * 192 + (phys >> 3);
    const int bh = logical >> 5;       // 0..47  (consecutive logicals share bh)
    const int qt = logical & 31;
    const int b  = bh / H;
    const int h  = bh % H;
    const int q0 = qt * 64 + w * 16;
    const int q  = q0 + col;           // this lane's q row

    __shared__ float am_lds[2048];
    __shared__ __align__(16) unsigned short P_lds[4][16][72];

    // stage amask row for this b (once)
    {
        const float4* amr = reinterpret_cast<const float4*>(amask + (size_t)b * S);
        float4* dst = reinterpret_cast<float4*>(am_lds);
        dst[threadIdx.x]       = amr[threadIdx.x];
        dst[threadIdx.x + 256] = amr[threadIdx.x + 256];
    }
    __syncthreads();

    // Q B-fragments (Q pre-scaled by 1/sqrt(D)); lane holds q = col
    const unsigned short* Qp = Qb + ((size_t)bh * S + q) * 64 + 8 * g;
    const bf16x8 bq0 = *reinterpret_cast<const bf16x8*>(Qp);
    const bf16x8 bq1 = *reinterpret_cast<const bf16x8*>(Qp + 32);

    f32x4 octx[4] = {};                 // ctx^T: col=q, row d = ds*16 + 4g + i
    float m_run = -1e30f, l_run = 0.0f; // per-lane scalars (one q per lane)

    const float* dmr = dmask + (size_t)b * S * S + (size_t)q * S;

#define DM_PREF(dst, kvv)                                                           \
    _Pragma("unroll")                                                               \
    for (int s = 0; s < 4; ++s)                                                     \
        dst[s] = *reinterpret_cast<const f32x4*>(dmr + (kvv) + s * 16 + 4 * g);

#define ATTN_TILE(KV, DM)                                                           \
    {                                                                               \
        /* QK^T swapped: A=K (m=k), B=Q (n=q) -> P^T, lane: q=col, k=s*16+4g+i */   \
        f32x4 sc[4] = {};                                                           \
        _Pragma("unroll")                                                           \
        for (int s = 0; s < 4; ++s) {                                               \
            const unsigned short* Kp = Kb + ((size_t)bh * S + (KV) + s * 16 + col) * 64 + 8 * g; \
            bf16x8 k0 = *reinterpret_cast<const bf16x8*>(Kp);                       \
            bf16x8 k1 = *reinterpret_cast<const bf16x8*>(Kp + 32);                  \
            sc[s] = MFMA16(k0, bq0, sc[s]);                                         \
            sc[s] = MFMA16(k1, bq1, sc[s]);                                         \
        }                                                                           \
        /* masks: dmask prefetched, amask from LDS */                               \
        _Pragma("unroll")                                                           \
        for (int s = 0; s < 4; ++s) {                                               \
            f32x4 a4 = *reinterpret_cast<const f32x4*>(am_lds + (KV) + s * 16 + 4 * g); \
            sc[s] += DM[s] + a4;                                                    \
        }                                                                           \
        /* softmax over k (per-lane 16 vals + reduce across g groups) */            \
        float tm = sc[0][0];                                                        \
        _Pragma("unroll")                                                           \
        for (int s = 0; s < 4; ++s)                                                 \
            _Pragma("unroll")                                                       \
            for (int i = 0; i < 4; ++i) tm = fmaxf(tm, sc[s][i]);                   \
        tm = fmaxf(tm, __shfl_xor(tm, 16));                                         \
        tm = fmaxf(tm, __shfl_xor(tm, 32));                                         \
        const bool grow = tm > m_run;                                               \
        const float mn = fmaxf(m_run, tm);                                          \
        float rs = 0.0f;                                                            \
        _Pragma("unroll")                                                           \
        for (int s = 0; s < 4; ++s)                                                 \
            _Pragma("unroll")                                                       \
            for (int i = 0; i < 4; ++i) {                                           \
                const float p = __expf(sc[s][i] - mn);                              \
                sc[s][i] = p;                                                       \
                rs += p;                                                            \
            }                                                                       \
        rs += __shfl_xor(rs, 16);                                                   \
        rs += __shfl_xor(rs, 32);                                                   \
        if (__any(grow)) {                                                          \
            const float sf = __expf(m_run - mn);                                    \
            l_run = l_run * sf + rs;                                                \
            m_run = mn;                                                             \
            _Pragma("unroll")                                                       \
            for (int ds_ = 0; ds_ < 4; ++ds_) octx[ds_] *= sf;                      \
        } else {                                                                    \
            l_run += rs;                                                            \
        }                                                                           \
        /* pack P^T (lane: row q=col, k=s*16+4g+i) -> LDS A/B layout */             \
        _Pragma("unroll")                                                           \
        for (int s = 0; s < 4; ++s) {                                               \
            ushort4 u;                                                              \
            u.x = f32_to_bf16(sc[s][0]);                                            \
            u.y = f32_to_bf16(sc[s][1]);                                            \
            u.z = f32_to_bf16(sc[s][2]);                                            \
            u.w = f32_to_bf16(sc[s][3]);                                            \
            *reinterpret_cast<ushort4*>(&P_lds[w][col][s * 16 + 4 * g]) = u;        \
        }                                                                           \
        const bf16x8 pa0 = *reinterpret_cast<const bf16x8*>(&P_lds[w][col][8 * g]); \
        const bf16x8 pa1 = *reinterpret_cast<const bf16x8*>(&P_lds[w][col][32 + 8 * g]); \
        /* PV swapped: A=V^T (m=d), B=P (n=q) -> ctx^T accumulates with q=col */    \
        _Pragma("unroll")                                                           \
        for (int ds_ = 0; ds_ < 4; ++ds_) {                                         \
            const unsigned short* Vp = Vt + ((size_t)bh * 64 + ds_ * 16 + col) * 2048 + (KV) + 8 * g; \
            bf16x8 av0 = *reinterpret_cast<const bf16x8*>(Vp);                      \
            bf16x8 av1 = *reinterpret_cast<const bf16x8*>(Vp + 32);                 \
            octx[ds_] = MFMA16(av0, pa0, octx[ds_]);                                \
            octx[ds_] = MFMA16(av1, pa1, octx[ds_]);                                \
        }                                                                           \
    }

    f32x4 dmA[4], dmB[4];
    DM_PREF(dmA, 0)
    for (int kv = 0; kv < S; kv += 128) {
        DM_PREF(dmB, kv + 64)
        ATTN_TILE(kv, dmA)
        if (kv + 128 < S) { DM_PREF(dmA, kv + 128) }
        ATTN_TILE(kv + 64, dmB)
    }

    // epilogue: out[b][q][h*64 + d], d = ds*16 + 4g + i -> contiguous float4
    const float inv = 1.0f / l_run;
#pragma unroll
    for (int ds_ = 0; ds_ < 4; ++ds_) {
        f32x4 o = octx[ds_] * inv;
        *reinterpret_cast<f32x4*>(out + ((size_t)b * S + q) * 768 + h * 64 + ds_ * 16 + 4 * g) = o;
    }
#undef ATTN_TILE
#undef DM_PREF
}

extern "C" void kernel_launch(void* const* d_in, const int* in_sizes, int n_in,
                              void* d_out, int out_size, void* d_ws, size_t ws_size,
                              hipStream_t stream) {
    const float* hidden = (const float*)d_in[0];
    const float* amask  = (const float*)d_in[1];
    const float* dmask  = (const float*)d_in[2];
    const float* Wq     = (const float*)d_in[3];
    const float* bq     = (const float*)d_in[4];
    const float* Wk     = (const float*)d_in[5];
    const float* bk     = (const float*)d_in[6];
    const float* Wv     = (const float*)d_in[7];
    const float* bv     = (const float*)d_in[8];
    float* out = (float*)d_out;

    // workspace layout (bf16 elements)
    unsigned short* Xb = (unsigned short*)d_ws;      // 8192*768
    unsigned short* Wb = Xb + 6291456;               // 2304*768
    unsigned short* Qb = Wb + 1769472;               // 48*2048*64
    unsigned short* Kb = Qb + 6291456;
    unsigned short* Vt = Kb + 6291456;               // [bh][d][s]

    cvt_f32_bf16<<<6144, 256, 0, stream>>>(hidden, Xb, 1572864);
    cvt_weights<<<1728, 256, 0, stream>>>(Wq, Wk, Wv, Wb);
    qkv_gemm<<<dim3(18, 64), 256, 0, stream>>>(Xb, Wb, bq, bk, bv, Qb, Kb, Vt);
    attn_kernel<<<1536, 256, 0, stream>>>(Qb, Kb, Vt, amask, dmask, out);
}

// Round 4
// 318.106 us; speedup vs baseline: 2.5380x; 2.0294x over previous
//
#include <hip/hip_runtime.h>

// BERT self-attention fused forward, MI355X (gfx950)
// B=4, S=2048, E=768, H=12, D=64
// Round 4: attn is L2-BW-bound (K/V read 4x per block x 32 qblocks = 3.2 GB L2).
//  - attn: K/V staged once per block in LDS (global_load_lds w=16, pre-swizzled
//    source, double-buffered, 1 barrier/tile); qblock 128 (wave owns 32 q);
//    grid 768 = exactly 3 blocks/CU; verified swapped 16x16x32 layouts kept.
//  - gemm: V stored row-major (kills 2B stride-4KB scatter); separate LDS
//    transpose kernel builds Vt; Vt aliases Xb region (ws unchanged).

typedef __bf16 bf16x8 __attribute__((ext_vector_type(8)));
typedef float f32x4 __attribute__((ext_vector_type(4)));
typedef unsigned short u16x8 __attribute__((ext_vector_type(8)));

#define MFMA16(a, b, c) __builtin_amdgcn_mfma_f32_16x16x32_bf16((a), (b), (c), 0, 0, 0)

__device__ __forceinline__ unsigned short f32_to_bf16(float f) {
    unsigned int u = __builtin_bit_cast(unsigned int, f);
    u += 0x7FFFu + ((u >> 16) & 1u);   // round-to-nearest-even
    return (unsigned short)(u >> 16);
}

__device__ __forceinline__ void gload_lds16(const void* g, void* l) {
    __builtin_amdgcn_global_load_lds(
        (const __attribute__((address_space(1))) void*)g,
        (__attribute__((address_space(3))) void*)l, 16, 0, 0);
}

__global__ __launch_bounds__(256) void cvt_f32_bf16(const float* __restrict__ src,
                                                    unsigned short* __restrict__ dst, int n4) {
    int i = blockIdx.x * 256 + threadIdx.x;
    if (i < n4) {
        const float4 v = reinterpret_cast<const float4*>(src)[i];
        ushort4 o;
        o.x = f32_to_bf16(v.x);
        o.y = f32_to_bf16(v.y);
        o.z = f32_to_bf16(v.z);
        o.w = f32_to_bf16(v.w);
        reinterpret_cast<ushort4*>(dst)[i] = o;
    }
}

__global__ __launch_bounds__(256) void cvt_weights(const float* __restrict__ Wq,
                                                   const float* __restrict__ Wk,
                                                   const float* __restrict__ Wv,
                                                   unsigned short* __restrict__ Wb) {
    int i = blockIdx.x * 256 + threadIdx.x;   // 0 .. 3*147456-1
    const float* src;
    int local = i;
    if (i < 147456) {
        src = Wq;
    } else if (i < 294912) {
        src = Wk; local = i - 147456;
    } else {
        src = Wv; local = i - 294912;
    }
    const float4 v = reinterpret_cast<const float4*>(src)[local];
    ushort4 o;
    o.x = f32_to_bf16(v.x);
    o.y = f32_to_bf16(v.y);
    o.z = f32_to_bf16(v.z);
    o.w = f32_to_bf16(v.w);
    reinterpret_cast<ushort4*>(Wb)[i] = o;
}

// QKV GEMM, m97 structure: out[m][n] = sum_k X[m][k]*W[n][k] + bias[n]
// All three outputs row-major [bh][s][d]. Q pre-scaled by 1/sqrt(64).
__global__ __launch_bounds__(256) void qkv_gemm(const unsigned short* __restrict__ Xb,
                                                const unsigned short* __restrict__ Wb,
                                                const float* __restrict__ bq,
                                                const float* __restrict__ bk,
                                                const float* __restrict__ bv,
                                                unsigned short* __restrict__ Qb,
                                                unsigned short* __restrict__ Kb,
                                                unsigned short* __restrict__ Vb) {
    const int K = 768;
    __shared__ __align__(16) unsigned short Abuf[128 * 32];
    __shared__ __align__(16) unsigned short Bbuf[128 * 32];

    const int lane = threadIdx.x & 63;
    const int w    = threadIdx.x >> 6;
    const int col  = lane & 15;
    const int g    = lane >> 4;
    const int m0 = blockIdx.y * 128;
    const int n0 = blockIdx.x * 128;
    const int wm = w >> 1, wn = w & 1;

    const int srow = w * 16 + (lane >> 2);
    const int scol = (lane & 3) * 8;
    const unsigned short* gA0 = Xb + (size_t)(m0 + srow) * K + scol;
    const unsigned short* gA1 = gA0 + (size_t)64 * K;
    const unsigned short* gB0 = Wb + (size_t)(n0 + srow) * K + scol;
    const unsigned short* gB1 = gB0 + (size_t)64 * K;
    char* lA0 = (char*)Abuf + w * 1024;
    char* lA1 = (char*)Abuf + 4096 + w * 1024;
    char* lB0 = (char*)Bbuf + w * 1024;
    char* lB1 = (char*)Bbuf + 4096 + w * 1024;

    f32x4 acc[4][4] = {};
    for (int k0 = 0; k0 < K; k0 += 32) {
        __syncthreads();
        gload_lds16(gA0 + k0, lA0);
        gload_lds16(gA1 + k0, lA1);
        gload_lds16(gB0 + k0, lB0);
        gload_lds16(gB1 + k0, lB1);
        __syncthreads();
        bf16x8 a[4], bfr[4];
#pragma unroll
        for (int t = 0; t < 4; ++t) {
            a[t]   = *reinterpret_cast<const bf16x8*>(Abuf + (wm * 64 + t * 16 + col) * 32 + 8 * g);
            bfr[t] = *reinterpret_cast<const bf16x8*>(Bbuf + (wn * 64 + t * 16 + col) * 32 + 8 * g);
        }
#pragma unroll
        for (int mi = 0; mi < 4; ++mi)
#pragma unroll
            for (int ni = 0; ni < 4; ++ni)
                acc[mi][ni] = MFMA16(a[mi], bfr[ni], acc[mi][ni]);
    }

    const int which = n0 / 768;  // 0=Q,1=K,2=V (uniform: 768 % 128 == 0)
    const float* bias = (which == 0) ? bq : (which == 1) ? bk : bv;
    const float scale = (which == 0) ? 0.125f : 1.0f;
    unsigned short* dst = (which == 0) ? Qb : (which == 1) ? Kb : Vb;

#pragma unroll
    for (int ni = 0; ni < 4; ++ni) {
        const int n = n0 + wn * 64 + ni * 16 + col;
        const int e = n - which * 768;
        const int h = e >> 6;
        const int d = e & 63;
        const float bb = bias[e];
#pragma unroll
        for (int mi = 0; mi < 4; ++mi)
#pragma unroll
            for (int i = 0; i < 4; ++i) {
                const int m   = m0 + wm * 64 + mi * 16 + 4 * g + i;
                const int bh  = (m >> 11) * 12 + h;
                const int srw = m & 2047;
                const float v = (acc[mi][ni][i] + bb) * scale;
                dst[((size_t)bh * 2048 + srw) * 64 + d] = f32_to_bf16(v);
            }
    }
}

// V row-major [bh][s][64] -> Vt [bh][64][2048], 64x64 LDS tiles
__global__ __launch_bounds__(256) void transpose_v(const unsigned short* __restrict__ Vb,
                                                   unsigned short* __restrict__ Vt) {
    __shared__ unsigned short T[64][72];
    const int bh = blockIdx.y;
    const int s0 = blockIdx.x * 64;
    const int t  = threadIdx.x;
    const int r  = t >> 2;          // 0..63
    const int c0 = (t & 3) * 16;    // 0,16,32,48

    const unsigned short* src = Vb + ((size_t)bh * 2048 + s0 + r) * 64 + c0;
    u16x8 a = *reinterpret_cast<const u16x8*>(src);
    u16x8 b = *reinterpret_cast<const u16x8*>(src + 8);
#pragma unroll
    for (int j = 0; j < 8; ++j) {
        T[c0 + j][r]     = a[j];
        T[c0 + 8 + j][r] = b[j];
    }
    __syncthreads();
    unsigned short* dstp = Vt + ((size_t)bh * 64 + r) * 2048 + s0 + c0;
    *reinterpret_cast<u16x8*>(dstp)     = *reinterpret_cast<const u16x8*>(&T[r][c0]);
    *reinterpret_cast<u16x8*>(dstp + 8) = *reinterpret_cast<const u16x8*>(&T[r][c0 + 8]);
}

// Flash attention. Grid 768 (48 bh x 16 qtiles), block 256 = 4 waves,
// wave owns 32 q rows (2 x 16-col groups). K/V LDS-staged, double-buffered.
__global__ __launch_bounds__(256, 3) void attn_kernel(const unsigned short* __restrict__ Qb,
                                                      const unsigned short* __restrict__ Kb,
                                                      const unsigned short* __restrict__ Vt,
                                                      const float* __restrict__ amask,
                                                      const float* __restrict__ dmask,
                                                      float* __restrict__ out) {
    const int S = 2048, H = 12;
    const int lane = threadIdx.x & 63;
    const int w    = threadIdx.x >> 6;
    const int col  = lane & 15;
    const int g    = lane >> 4;

    // bijective XCD swizzle: 768 = 8 XCD x 96; consecutive logicals share bh
    const int phys    = blockIdx.x;
    const int logical = (phys & 7) * 96 + (phys >> 3);
    const int bh = logical >> 4;       // 0..47
    const int qt = logical & 15;
    const int b  = bh / H;
    const int h  = bh % H;
    const int q0 = qt * 128 + w * 32;  // wave's first q row

    // K/V tiles, swizzled 16B chunks within 128B rows: slot = chunk ^ (row&7)
    __shared__ __align__(16) unsigned short Kl[2][4096];   // [64 kv][64 d]
    __shared__ __align__(16) unsigned short Vl[2][4096];   // [64 d][64 kv]
    __shared__ __align__(16) unsigned short Pl[4][32][72]; // per-wave P, pad 72

    // Q B-fragments (Q pre-scaled): qg in {0,1}, kst in {0,1}
    bf16x8 qf[2][2];
#pragma unroll
    for (int qg = 0; qg < 2; ++qg)
#pragma unroll
        for (int kst = 0; kst < 2; ++kst)
            qf[qg][kst] = *reinterpret_cast<const bf16x8*>(
                Qb + ((size_t)bh * S + q0 + qg * 16 + col) * 64 + kst * 32 + 8 * g);

    f32x4 octx[2][4] = {};
    float m_run[2] = {-1e30f, -1e30f}, l_run[2] = {0.0f, 0.0f};

    const float* dmr0 = dmask + (size_t)b * S * S + (size_t)(q0 + col) * S;
    const float* dmr1 = dmr0 + (size_t)16 * S;
    const float* amr  = amask + (size_t)b * S;

    // staging: per wave 2 calls x 1KB for each of K,V; linear LDS dest,
    // per-lane pre-swizzled global source.
#define STAGE(buf, KV)                                                              \
    {                                                                               \
        _Pragma("unroll")                                                           \
        for (int c = 0; c < 2; ++c) {                                               \
            const int base = w * 2048 + c * 1024;          /* uniform */            \
            const int o    = base + (lane << 4);                                    \
            const int row  = o >> 7;                                                \
            const int slot = (o >> 4) & 7;                                          \
            const int chunk = slot ^ (row & 7);                                     \
            gload_lds16((const char*)(Kb + ((size_t)bh * S + (KV) + row) * 64) + chunk * 16, \
                        (char*)&Kl[buf][0] + base);                                 \
            gload_lds16((const char*)(Vt + ((size_t)bh * 64 + row) * S + (KV)) + chunk * 16, \
                        (char*)&Vl[buf][0] + base);                                 \
        }                                                                           \
    }

    STAGE(0, 0)
    __syncthreads();

    int cur = 0;
    for (int t = 0; t < 32; ++t) {
        const int kv = t * 64;
        if (t + 1 < 32) STAGE(cur ^ 1, kv + 64)

        // dmask + amask loads (issued early; consumed after QK^T)
        f32x4 dm[2][4], am4[4];
#pragma unroll
        for (int s = 0; s < 4; ++s) {
            dm[0][s] = *reinterpret_cast<const f32x4*>(dmr0 + kv + s * 16 + 4 * g);
            dm[1][s] = *reinterpret_cast<const f32x4*>(dmr1 + kv + s * 16 + 4 * g);
            am4[s]   = *reinterpret_cast<const f32x4*>(amr  + kv + s * 16 + 4 * g);
        }

        // ---- QK^T (swapped): A=K frag (m=kv), B=Q (n=q) -> sc col=q, row=kv ----
        f32x4 sc[2][4] = {};
#pragma unroll
        for (int s = 0; s < 4; ++s) {
            const int row = s * 16 + col;
#pragma unroll
            for (int kst = 0; kst < 2; ++kst) {
                bf16x8 kf = *reinterpret_cast<const bf16x8*>(
                    (const char*)&Kl[cur][0] + row * 128 + (((g + 4 * kst) ^ (col & 7)) << 4));
                sc[0][s] = MFMA16(kf, qf[0][kst], sc[0][s]);
                sc[1][s] = MFMA16(kf, qf[1][kst], sc[1][s]);
            }
        }

#pragma unroll
        for (int qg = 0; qg < 2; ++qg) {
            // masks
#pragma unroll
            for (int s = 0; s < 4; ++s) sc[qg][s] += dm[qg][s] + am4[s];
            // softmax over kv (16 in-lane + cross-g reduce)
            float tm = sc[qg][0][0];
#pragma unroll
            for (int s = 0; s < 4; ++s)
#pragma unroll
                for (int i = 0; i < 4; ++i) tm = fmaxf(tm, sc[qg][s][i]);
            tm = fmaxf(tm, __shfl_xor(tm, 16));
            tm = fmaxf(tm, __shfl_xor(tm, 32));
            const bool grow = tm > m_run[qg];
            const float mn = fmaxf(m_run[qg], tm);
            float rs = 0.0f;
#pragma unroll
            for (int s = 0; s < 4; ++s)
#pragma unroll
                for (int i = 0; i < 4; ++i) {
                    const float p = __expf(sc[qg][s][i] - mn);
                    sc[qg][s][i] = p;
                    rs += p;
                }
            rs += __shfl_xor(rs, 16);
            rs += __shfl_xor(rs, 32);
            if (__any(grow)) {
                const float sf = __expf(m_run[qg] - mn);
                l_run[qg] = l_run[qg] * sf + rs;
                m_run[qg] = mn;
#pragma unroll
                for (int ds_ = 0; ds_ < 4; ++ds_) octx[qg][ds_] *= sf;
            } else {
                l_run[qg] += rs;
            }
            // pack P^T -> per-wave LDS
#pragma unroll
            for (int s = 0; s < 4; ++s) {
                ushort4 u;
                u.x = f32_to_bf16(sc[qg][s][0]);
                u.y = f32_to_bf16(sc[qg][s][1]);
                u.z = f32_to_bf16(sc[qg][s][2]);
                u.w = f32_to_bf16(sc[qg][s][3]);
                *reinterpret_cast<ushort4*>(&Pl[w][qg * 16 + col][s * 16 + 4 * g]) = u;
            }
        }

        // ---- PV (swapped): A=V^T frag (m=d), B=P (n=q) ----
        bf16x8 pb[2][2];
#pragma unroll
        for (int qg = 0; qg < 2; ++qg)
#pragma unroll
            for (int kst = 0; kst < 2; ++kst)
                pb[qg][kst] = *reinterpret_cast<const bf16x8*>(
                    &Pl[w][qg * 16 + col][kst * 32 + 8 * g]);
#pragma unroll
        for (int ds_ = 0; ds_ < 4; ++ds_) {
            const int row = ds_ * 16 + col;
#pragma unroll
            for (int kst = 0; kst < 2; ++kst) {
                bf16x8 vf = *reinterpret_cast<const bf16x8*>(
                    (const char*)&Vl[cur][0] + row * 128 + (((g + 4 * kst) ^ (col & 7)) << 4));
                octx[0][ds_] = MFMA16(vf, pb[0][kst], octx[0][ds_]);
                octx[1][ds_] = MFMA16(vf, pb[1][kst], octx[1][ds_]);
            }
        }

        __syncthreads();
        cur ^= 1;
    }

    // epilogue
#pragma unroll
    for (int qg = 0; qg < 2; ++qg) {
        const float inv = 1.0f / l_run[qg];
        const size_t ob = ((size_t)b * S + q0 + qg * 16 + col) * 768 + h * 64;
#pragma unroll
        for (int ds_ = 0; ds_ < 4; ++ds_) {
            f32x4 o = octx[qg][ds_] * inv;
            *reinterpret_cast<f32x4*>(out + ob + ds_ * 16 + 4 * g) = o;
        }
    }
#undef STAGE
}

extern "C" void kernel_launch(void* const* d_in, const int* in_sizes, int n_in,
                              void* d_out, int out_size, void* d_ws, size_t ws_size,
                              hipStream_t stream) {
    const float* hidden = (const float*)d_in[0];
    const float* amask  = (const float*)d_in[1];
    const float* dmask  = (const float*)d_in[2];
    const float* Wq     = (const float*)d_in[3];
    const float* bq     = (const float*)d_in[4];
    const float* Wk     = (const float*)d_in[5];
    const float* bk     = (const float*)d_in[6];
    const float* Wv     = (const float*)d_in[7];
    const float* bv     = (const float*)d_in[8];
    float* out = (float*)d_out;

    // workspace layout (bf16 elements); Vt reuses Xb region (dead after gemm)
    unsigned short* Xb = (unsigned short*)d_ws;      // 8192*768
    unsigned short* Wb = Xb + 6291456;               // 2304*768
    unsigned short* Qb = Wb + 1769472;               // 48*2048*64
    unsigned short* Kb = Qb + 6291456;
    unsigned short* Vb = Kb + 6291456;               // row-major V
    unsigned short* Vt = Xb;                         // transposed [bh][d][s]

    cvt_f32_bf16<<<6144, 256, 0, stream>>>(hidden, Xb, 1572864);
    cvt_weights<<<1728, 256, 0, stream>>>(Wq, Wk, Wv, Wb);
    qkv_gemm<<<dim3(18, 64), 256, 0, stream>>>(Xb, Wb, bq, bk, bv, Qb, Kb, Vb);
    transpose_v<<<dim3(32, 48), 256, 0, stream>>>(Vb, Vt);
    attn_kernel<<<768, 256, 0, stream>>>(Qb, Kb, Vt, amask, dmask, out);
}